// Round 12
// baseline (62.775 us; speedup 1.0000x reference)
//
#include <hip/hip_runtime.h>
#include <math.h>
#include <stdint.h>

// Router: scores = x @ emb^T [32768 x 64] fp32-accurate, top-2 + 2-way softmax.
//
// Error-free split-bf16 MFMA (rounds 9-11, passes): 3 bf16 limbs per fp32
// operand, 6 limb-product MFMA passes accumulated in fp32 (~3e-7 error).
// SPLIT-K x4 (round 11): block = 4 waves = one 16-token tile, wave w owns K
// quarter [256w, 256w+256); grid 2048 blocks -> 66% occupancy measured.
// Round-11 flaw: __launch_bounds__(256,8) squeezed the kernel into 32 VGPRs
// -> zero scheduling slack, every load consumed back-to-back (all pipes ~11%).
// This round: (256,4) = 128 VGPRs, kk-loop FULLY UNROLLED with all 16 x-loads
// written straight-line up front -- the scheduler hoists independent loads as
// far as registers allow (2-4 kk of cover ~ HBM latency), interleaved with
// 192 MFMAs. 4 waves/SIMD x deep MLP finally covers the latency chain.
// Spill tripwire: WRITE_SIZE must stay ~8.2 MB.

typedef __attribute__((ext_vector_type(8))) short short8;
typedef __attribute__((ext_vector_type(4))) float f32x4;

constexpr int HDIM = 1024;
constexpr int NEXP = 64;
constexpr int TPB  = 16;            // tokens per block (one M-tile)
constexpr int NTHREADS = 256;
constexpr int NKKW = 8;             // kk steps of 32 per wave (K quarter)

__device__ __forceinline__ uint32_t cvtpk_bf16(float lo, float hi) {
    uint32_t r;
    asm("v_cvt_pk_bf16_f32 %0, %1, %2" : "=v"(r) : "v"(lo), "v"(hi));
    return r;
}

// RNE 3-limb bf16 split of 8 fp32 values; outputs packed frag words.
__device__ __forceinline__ void split8(const float4& A, const float4& B,
                                       uint32_t w0[4], uint32_t w1[4],
                                       uint32_t w2[4])
{
    const float p[8] = {A.x, A.y, A.z, A.w, B.x, B.y, B.z, B.w};
#pragma unroll
    for (int m = 0; m < 4; ++m) {
        const float lo = p[2 * m], hi = p[2 * m + 1];
        const uint32_t c0 = cvtpk_bf16(lo, hi);
        const float l0 = __uint_as_float(c0 << 16);
        const float h0 = __uint_as_float(c0 & 0xFFFF0000u);
        const float rl = lo - l0, rh = hi - h0;         // exact
        const uint32_t c1 = cvtpk_bf16(rl, rh);
        const float l1 = __uint_as_float(c1 << 16);
        const float h1 = __uint_as_float(c1 & 0xFFFF0000u);
        const uint32_t c2 = cvtpk_bf16(rl - l1, rh - h1);
        w0[m] = c0; w1[m] = c1; w2[m] = c2;
    }
}

__device__ __forceinline__ short8 frag_of(uint32_t a, uint32_t b,
                                          uint32_t c, uint32_t d) {
    union { uint4 u; short8 s; } cv;
    cv.u = make_uint4(a, b, c, d);
    return cv.s;
}
__device__ __forceinline__ short8 frag_of4(const uint4& v) {
    union { uint4 u; short8 s; } cv;
    cv.u = v;
    return cv.s;
}

// prepack: B-frags for mfma. wsb[f] with f=[kk][t][lane]: lane l holds
// emb[t*16+(l&15)][kk*32+(l>>4)*8 .. +7] as bf16x8; three limb arrays.
__global__ __launch_bounds__(256)
void prepack_kernel(const float* __restrict__ emb, uint4* __restrict__ wsb)
{
    const int f  = blockIdx.x * 256 + threadIdx.x;   // 0..8191
    const int l  = f & 63, t = (f >> 6) & 3, kk = f >> 8;
    const int e  = t * 16 + (l & 15);
    const int k0 = kk * 32 + (l >> 4) * 8;
    const float4 A = *(const float4*)(emb + (size_t)e * HDIM + k0);
    const float4 B = *(const float4*)(emb + (size_t)e * HDIM + k0 + 4);
    uint32_t w0[4], w1[4], w2[4];
    split8(A, B, w0, w1, w2);
    wsb[f]         = make_uint4(w0[0], w0[1], w0[2], w0[3]);
    wsb[f + 8192]  = make_uint4(w1[0], w1[1], w1[2], w1[3]);
    wsb[f + 16384] = make_uint4(w2[0], w2[1], w2[2], w2[3]);
}

__global__ __launch_bounds__(NTHREADS, 4)
void router_kernel(const float* __restrict__ x,
                   const uint4* __restrict__ wsb,
                   float* __restrict__ out)
{
    __shared__ f32x4  part[4][4][64];   // [kq][tile][lane]  16 KiB
    __shared__ float4 cand[4][TPB];     // [egrp][token] raw (V1,E1,V2,E2)
    __shared__ float4 cand2[TPB];       // [token] (p1,p2,E1,E2)

    const int tid  = threadIdx.x;
    const int lane = tid & 63;
    const int wq   = tid >> 6;       // wave id = K-quarter; also tile owner
    const int tok0 = blockIdx.x * TPB;
    const int col  = lane & 15;      // token row (A) / expert col (C)
    const int grp  = lane >> 4;

    // A source: lane holds token (tok0+col), k-slice grp*8..+7 within each kk
    const float* xrow = x + (size_t)(tok0 + col) * HDIM + wq * 256 + grp * 8;

    f32x4 acc[4] = {{0,0,0,0}, {0,0,0,0}, {0,0,0,0}, {0,0,0,0}};

    // ---- all 16 x loads straight-line (independent; scheduler hoists as far
    // as the 128-reg budget allows -> deep MLP) ----
    float4 xq[NKKW][2];
#pragma unroll
    for (int kk = 0; kk < NKKW; ++kk) {
        xq[kk][0] = *(const float4*)(xrow + kk * 32);
        xq[kk][1] = *(const float4*)(xrow + kk * 32 + 4);
    }

#pragma unroll
    for (int kk = 0; kk < NKKW; ++kk) {
        uint32_t w0[4], w1[4], w2[4];
        split8(xq[kk][0], xq[kk][1], w0, w1, w2);
        const short8 fa0 = frag_of(w0[0], w0[1], w0[2], w0[3]);
        const short8 fa1 = frag_of(w1[0], w1[1], w1[2], w1[3]);
        const short8 fa2 = frag_of(w2[0], w2[1], w2[2], w2[3]);

        const int fbase = (wq * NKKW + kk) * 256 + lane;
#pragma unroll
        for (int t = 0; t < 4; ++t) {
            const short8 fb0 = frag_of4(wsb[fbase + t * 64]);
            const short8 fb1 = frag_of4(wsb[8192 + fbase + t * 64]);
            const short8 fb2 = frag_of4(wsb[16384 + fbase + t * 64]);
            f32x4 a = acc[t];
            a = __builtin_amdgcn_mfma_f32_16x16x32_bf16(fa2, fb0, a, 0, 0, 0);
            a = __builtin_amdgcn_mfma_f32_16x16x32_bf16(fa0, fb2, a, 0, 0, 0);
            a = __builtin_amdgcn_mfma_f32_16x16x32_bf16(fa1, fb1, a, 0, 0, 0);
            a = __builtin_amdgcn_mfma_f32_16x16x32_bf16(fa1, fb0, a, 0, 0, 0);
            a = __builtin_amdgcn_mfma_f32_16x16x32_bf16(fa0, fb1, a, 0, 0, 0);
            a = __builtin_amdgcn_mfma_f32_16x16x32_bf16(fa0, fb0, a, 0, 0, 0);
            acc[t] = a;
        }
    }

    // ---- split-K reduce: wave wq owns tile wq (fixed order = deterministic)
#pragma unroll
    for (int t = 0; t < 4; ++t) part[wq][t][lane] = acc[t];
    __syncthreads();

    f32x4 fin = part[0][wq][lane];
#pragma unroll
    for (int q = 1; q < 4; ++q) fin += part[q][wq][lane];

    // ---- per-wave top-2 over this tile's 16 expert cols, per token reg ----
#define INS(v, e)                                                              \
    do {                                                                       \
        const float _v = (v); const int _e = (e);                              \
        if (_v > V1 || (_v == V1 && _e < E1)) {                                \
            V2 = V1; E2 = E1; V1 = _v; E1 = _e;                                \
        } else if (_v > V2 || (_v == V2 && _e < E2)) {                         \
            V2 = _v; E2 = _e;                                                  \
        }                                                                      \
    } while (0)

#pragma unroll
    for (int i = 0; i < 4; ++i) {
        float V1 = fin[i]; int E1 = wq * 16 + col;
        float V2 = -INFINITY; int E2 = NEXP;
#pragma unroll
        for (int m = 1; m <= 8; m <<= 1) {
            const float pv1 = __shfl_xor(V1, m, 64);
            const int   pe1 = __shfl_xor(E1, m, 64);
            const float pv2 = __shfl_xor(V2, m, 64);
            const int   pe2 = __shfl_xor(E2, m, 64);
            INS(pv1, pe1);
            INS(pv2, pe2);
        }
        if (col == 0) {
            float4 c;
            c.x = V1; c.y = __int_as_float(E1);
            c.z = V2; c.w = __int_as_float(E2);
            cand[wq][grp * 4 + i] = c;
        }
    }
    __syncthreads();

    // ---- merge 4 expert groups per token (ascending group, lowest-idx ties)
    if (tid < TPB) {
        float V1 = -INFINITY, V2 = -INFINITY; int E1 = 0, E2 = 0;
#pragma unroll
        for (int ww = 0; ww < 4; ++ww) {
            const float4 q = cand[ww][tid];
            const float a = q.x; const int ea = __float_as_int(q.y);
            const float b = q.z; const int eb = __float_as_int(q.w);
            if (a > V1)      { V2 = V1; E2 = E1; V1 = a; E1 = ea; }
            else if (a > V2) { V2 = a; E2 = ea; }
            if (b > V1)      { V2 = V1; E2 = E1; V1 = b; E1 = eb; }
            else if (b > V2) { V2 = b; E2 = eb; }
        }
        const float et = expf(V2 - V1);
        float4 c2;
        c2.x = 1.f / (1.f + et);
        c2.y = et / (1.f + et);
        c2.z = __int_as_float(E1);
        c2.w = __int_as_float(E2);
        cand2[tid] = c2;
    }
#undef INS
    __syncthreads();

    // ---- coalesced output: 16 tokens x 16 quads = 256 float4 ----
    {
        const int tt = tid >> 4, q = tid & 15;
        const float4 c = cand2[tt];
        const int E1 = __float_as_int(c.z), E2 = __float_as_int(c.w);
        float4 o;
        float* of = (float*)&o;
#pragma unroll
        for (int ii = 0; ii < 4; ++ii) {
            const int e = 4 * q + ii;
            of[ii] = (e == E1) ? c.x : (e == E2) ? c.y : 0.f;
        }
        *(float4*)(out + (size_t)(tok0 + tt) * NEXP + q * 4) = o;
    }
}

extern "C" void kernel_launch(void* const* d_in, const int* in_sizes, int n_in,
                              void* d_out, int out_size, void* d_ws, size_t ws_size,
                              hipStream_t stream)
{
    const float* x   = (const float*)d_in[0];
    const float* emb = (const float*)d_in[1];
    float* out = (float*)d_out;
    uint4* wsb = (uint4*)d_ws;                   // 384 KiB: 3 limb B-frag arrays

    prepack_kernel<<<32, 256, 0, stream>>>(emb, wsb);

    const int n_tokens = in_sizes[0] / HDIM;     // 32768
    const int nblocks  = n_tokens / TPB;         // 2048

    router_kernel<<<nblocks, NTHREADS, 0, stream>>>(x, wsb, out);
}

// Round 13
// 61.029 us; speedup vs baseline: 1.0286x; 1.0286x over previous
//
#include <hip/hip_runtime.h>
#include <math.h>
#include <stdint.h>

// Router: scores = x @ emb^T [32768 x 64] fp32-accurate, top-2 + 2-way softmax.
//
// Error-free split-bf16 MFMA (rounds 9-12, passes): 3 bf16 limbs per fp32
// operand, 6 limb-product MFMA passes accumulated in fp32 (~3e-7 error).
// Rounds 10-12 proved hipcc sinks register-held VMEM loads to their uses
// (VGPR 44 vs 128 allowed) -> ~2 loads in flight/wave -> latency-bound at
// ~10% on every pipe. This round delivers MLP the compiler can't undo:
// x staged via global_load_lds DMA (no dest regs; whole 8KB chunk in flight),
// double-buffered, XOR-quad swizzle via pre-swizzled global source (proven
// 0-conflict, rounds 2-8). Block = 4 waves = 32 tokens; wave w owns expert
// tile w (16 experts, full K). Grid 1024 = 4 blocks/CU = 4 waves/SIMD.
// Per kk/wave: 4 ds_read_b128 + 2 splits + 3 B L2 loads + 12 MFMA.

typedef __attribute__((ext_vector_type(8))) short short8;
typedef __attribute__((ext_vector_type(4))) float f32x4;

constexpr int HDIM = 1024;
constexpr int NEXP = 64;
constexpr int TPB  = 32;            // tokens per block
constexpr int NTHREADS = 256;       // 4 waves
constexpr int NCHUNK = 16;          // 64-k chunks

__device__ __forceinline__ uint32_t cvtpk_bf16(float lo, float hi) {
    uint32_t r;
    asm("v_cvt_pk_bf16_f32 %0, %1, %2" : "=v"(r) : "v"(lo), "v"(hi));
    return r;
}

// RNE 3-limb bf16 split of 8 fp32 values; outputs packed frag words.
__device__ __forceinline__ void split8(const float4& A, const float4& B,
                                       uint32_t w0[4], uint32_t w1[4],
                                       uint32_t w2[4])
{
    const float p[8] = {A.x, A.y, A.z, A.w, B.x, B.y, B.z, B.w};
#pragma unroll
    for (int m = 0; m < 4; ++m) {
        const float lo = p[2 * m], hi = p[2 * m + 1];
        const uint32_t c0 = cvtpk_bf16(lo, hi);
        const float l0 = __uint_as_float(c0 << 16);
        const float h0 = __uint_as_float(c0 & 0xFFFF0000u);
        const float rl = lo - l0, rh = hi - h0;         // exact
        const uint32_t c1 = cvtpk_bf16(rl, rh);
        const float l1 = __uint_as_float(c1 << 16);
        const float h1 = __uint_as_float(c1 & 0xFFFF0000u);
        const uint32_t c2 = cvtpk_bf16(rl - l1, rh - h1);
        w0[m] = c0; w1[m] = c1; w2[m] = c2;
    }
}

__device__ __forceinline__ short8 frag_of(uint32_t a, uint32_t b,
                                          uint32_t c, uint32_t d) {
    union { uint4 u; short8 s; } cv;
    cv.u = make_uint4(a, b, c, d);
    return cv.s;
}
__device__ __forceinline__ short8 frag_of4(const uint4& v) {
    union { uint4 u; short8 s; } cv;
    cv.u = v;
    return cv.s;
}

// prepack: B-frags for mfma. wsb[f] with f=[kk][t][lane]: lane l holds
// emb[t*16+(l&15)][kk*32+(l>>4)*8 .. +7] as bf16x8; three limb arrays.
__global__ __launch_bounds__(256)
void prepack_kernel(const float* __restrict__ emb, uint4* __restrict__ wsb)
{
    const int f  = blockIdx.x * 256 + threadIdx.x;   // 0..8191
    const int l  = f & 63, t = (f >> 6) & 3, kk = f >> 8;
    const int e  = t * 16 + (l & 15);
    const int k0 = kk * 32 + (l >> 4) * 8;
    const float4 A = *(const float4*)(emb + (size_t)e * HDIM + k0);
    const float4 B = *(const float4*)(emb + (size_t)e * HDIM + k0 + 4);
    uint32_t w0[4], w1[4], w2[4];
    split8(A, B, w0, w1, w2);
    wsb[f]         = make_uint4(w0[0], w0[1], w0[2], w0[3]);
    wsb[f + 8192]  = make_uint4(w1[0], w1[1], w1[2], w1[3]);
    wsb[f + 16384] = make_uint4(w2[0], w2[1], w2[2], w2[3]);
}

__global__ __launch_bounds__(NTHREADS, 4)
void router_kernel(const float* __restrict__ x,
                   const uint4* __restrict__ wsb,
                   float* __restrict__ out)
{
    __shared__ float4 xs[2][TPB][16];   // 16 KiB, x[token][quad^(token&15)]
    __shared__ float4 cand[4][TPB];     // 2 KiB  (V1,E1,V2,E2) per wave/token
    __shared__ float4 cand2[TPB];       // 0.5 KiB (p1,p2,E1,E2) per token

    const int tid  = threadIdx.x;
    const int lane = tid & 63;
    const int w    = tid >> 6;          // expert tile: experts [16w, 16w+16)
    const int tok0 = blockIdx.x * TPB;
    const int col  = lane & 15;         // A row (token-in-16) / C expert col
    const int grp  = lane >> 4;         // k-slice within kk

    // Stage chunk C of x (32 rows x 64 k = 8 KB): linear LDS dest (wave-uniform
    // base + lane*16), XOR swizzle folded into the per-lane GLOBAL source.
#define STAGE(P, C)                                                            \
    do {                                                                       \
        _Pragma("unroll")                                                      \
        for (int jj = 0; jj < 2; ++jj) {                                       \
            const int g_ = jj * NTHREADS + tid;                                \
            const int r_ = g_ >> 4, q_ = g_ & 15;                              \
            const float* src = x + (size_t)(tok0 + r_) * HDIM + (C) * 64       \
                                 + ((q_ ^ (r_ & 15)) * 4);                     \
            __builtin_amdgcn_global_load_lds(                                  \
                (const __attribute__((address_space(1))) void*)src,            \
                (__attribute__((address_space(3))) void*)&xs[P][r_][q_],       \
                16, 0, 0);                                                     \
        }                                                                      \
    } while (0)

    f32x4 accA = {0, 0, 0, 0};          // tokens tok0+0..15   x 16 experts
    f32x4 accB = {0, 0, 0, 0};          // tokens tok0+16..31  x 16 experts

    STAGE(0, 0);
    int p = 0;

#pragma unroll 1
    for (int c = 0; c < NCHUNK; ++c) {
        __syncthreads();                           // xs[p] staged
        if (c + 1 < NCHUNK) STAGE(p ^ 1, c + 1);

#pragma unroll
        for (int j = 0; j < 2; ++j) {              // kk = 2c + j
            const int q0 = j * 8 + grp * 2;
            const float4 a0 = xs[p][col     ][(q0    ) ^ col];
            const float4 a1 = xs[p][col     ][(q0 + 1) ^ col];
            const float4 b0 = xs[p][col + 16][(q0    ) ^ col];
            const float4 b1 = xs[p][col + 16][(q0 + 1) ^ col];

            uint32_t wa0[4], wa1[4], wa2[4], wb0[4], wb1[4], wb2[4];
            split8(a0, a1, wa0, wa1, wa2);
            split8(b0, b1, wb0, wb1, wb2);
            const short8 fA0 = frag_of(wa0[0], wa0[1], wa0[2], wa0[3]);
            const short8 fA1 = frag_of(wa1[0], wa1[1], wa1[2], wa1[3]);
            const short8 fA2 = frag_of(wa2[0], wa2[1], wa2[2], wa2[3]);
            const short8 fB0 = frag_of(wb0[0], wb0[1], wb0[2], wb0[3]);
            const short8 fB1 = frag_of(wb1[0], wb1[1], wb1[2], wb1[3]);
            const short8 fB2 = frag_of(wb2[0], wb2[1], wb2[2], wb2[3]);

            const int fidx = (c * 2 + j) * 256 + w * 64 + lane;
            const short8 fb0 = frag_of4(wsb[fidx]);
            const short8 fb1 = frag_of4(wsb[8192 + fidx]);
            const short8 fb2 = frag_of4(wsb[16384 + fidx]);

            accA = __builtin_amdgcn_mfma_f32_16x16x32_bf16(fA2, fb0, accA, 0,0,0);
            accA = __builtin_amdgcn_mfma_f32_16x16x32_bf16(fA0, fb2, accA, 0,0,0);
            accA = __builtin_amdgcn_mfma_f32_16x16x32_bf16(fA1, fb1, accA, 0,0,0);
            accA = __builtin_amdgcn_mfma_f32_16x16x32_bf16(fA1, fb0, accA, 0,0,0);
            accA = __builtin_amdgcn_mfma_f32_16x16x32_bf16(fA0, fb1, accA, 0,0,0);
            accA = __builtin_amdgcn_mfma_f32_16x16x32_bf16(fA0, fb0, accA, 0,0,0);

            accB = __builtin_amdgcn_mfma_f32_16x16x32_bf16(fB2, fb0, accB, 0,0,0);
            accB = __builtin_amdgcn_mfma_f32_16x16x32_bf16(fB0, fb2, accB, 0,0,0);
            accB = __builtin_amdgcn_mfma_f32_16x16x32_bf16(fB1, fb1, accB, 0,0,0);
            accB = __builtin_amdgcn_mfma_f32_16x16x32_bf16(fB1, fb0, accB, 0,0,0);
            accB = __builtin_amdgcn_mfma_f32_16x16x32_bf16(fB0, fb1, accB, 0,0,0);
            accB = __builtin_amdgcn_mfma_f32_16x16x32_bf16(fB0, fb0, accB, 0,0,0);
        }
        p ^= 1;
    }
#undef STAGE

    // ---- top-2 epilogue. acc[i]: token grp*4+i (A) / 16+grp*4+i (B),
    // expert 16w+col. Reduce over the 16-lane group (masks 1,2,4,8),
    // lowest expert index wins exact ties.
#define INS(v, e)                                                              \
    do {                                                                       \
        const float _v = (v); const int _e = (e);                              \
        if (_v > V1 || (_v == V1 && _e < E1)) {                                \
            V2 = V1; E2 = E1; V1 = _v; E1 = _e;                                \
        } else if (_v > V2 || (_v == V2 && _e < E2)) {                         \
            V2 = _v; E2 = _e;                                                  \
        }                                                                      \
    } while (0)

#pragma unroll
    for (int i = 0; i < 4; ++i) {
        {
            float V1 = accA[i]; int E1 = 16 * w + col;
            float V2 = -INFINITY; int E2 = NEXP;
#pragma unroll
            for (int m = 1; m <= 8; m <<= 1) {
                const float pv1 = __shfl_xor(V1, m, 64);
                const int   pe1 = __shfl_xor(E1, m, 64);
                const float pv2 = __shfl_xor(V2, m, 64);
                const int   pe2 = __shfl_xor(E2, m, 64);
                INS(pv1, pe1);
                INS(pv2, pe2);
            }
            if (col == 0) {
                float4 cd;
                cd.x = V1; cd.y = __int_as_float(E1);
                cd.z = V2; cd.w = __int_as_float(E2);
                cand[w][grp * 4 + i] = cd;
            }
        }
        {
            float V1 = accB[i]; int E1 = 16 * w + col;
            float V2 = -INFINITY; int E2 = NEXP;
#pragma unroll
            for (int m = 1; m <= 8; m <<= 1) {
                const float pv1 = __shfl_xor(V1, m, 64);
                const int   pe1 = __shfl_xor(E1, m, 64);
                const float pv2 = __shfl_xor(V2, m, 64);
                const int   pe2 = __shfl_xor(E2, m, 64);
                INS(pv1, pe1);
                INS(pv2, pe2);
            }
            if (col == 0) {
                float4 cd;
                cd.x = V1; cd.y = __int_as_float(E1);
                cd.z = V2; cd.w = __int_as_float(E2);
                cand[w][16 + grp * 4 + i] = cd;
            }
        }
    }
    __syncthreads();

    // ---- merge 4 expert tiles per token (ascending tile => lowest-idx ties)
    if (tid < TPB) {
        float V1 = -INFINITY, V2 = -INFINITY; int E1 = 0, E2 = 0;
#pragma unroll
        for (int ww = 0; ww < 4; ++ww) {
            const float4 q = cand[ww][tid];
            const float a = q.x; const int ea = __float_as_int(q.y);
            const float b = q.z; const int eb = __float_as_int(q.w);
            if (a > V1)      { V2 = V1; E2 = E1; V1 = a; E1 = ea; }
            else if (a > V2) { V2 = a; E2 = ea; }
            if (b > V1)      { V2 = V1; E2 = E1; V1 = b; E1 = eb; }
            else if (b > V2) { V2 = b; E2 = eb; }
        }
        const float et = expf(V2 - V1);
        float4 c2;
        c2.x = 1.f / (1.f + et);
        c2.y = et / (1.f + et);
        c2.z = __int_as_float(E1);
        c2.w = __int_as_float(E2);
        cand2[tid] = c2;
    }
#undef INS
    __syncthreads();

    // ---- coalesced output: 32 tokens x 16 quads = 512 float4 ----
#pragma unroll
    for (int jj = 0; jj < 2; ++jj) {
        const int G = jj * NTHREADS + tid;     // 0..511
        const int tt = G >> 4, q = G & 15;
        const float4 c = cand2[tt];
        const int E1 = __float_as_int(c.z), E2 = __float_as_int(c.w);
        float4 o;
        float* of = (float*)&o;
#pragma unroll
        for (int ii = 0; ii < 4; ++ii) {
            const int e = 4 * q + ii;
            of[ii] = (e == E1) ? c.x : (e == E2) ? c.y : 0.f;
        }
        *(float4*)(out + (size_t)(tok0 + tt) * NEXP + q * 4) = o;
    }
}

extern "C" void kernel_launch(void* const* d_in, const int* in_sizes, int n_in,
                              void* d_out, int out_size, void* d_ws, size_t ws_size,
                              hipStream_t stream)
{
    const float* x   = (const float*)d_in[0];
    const float* emb = (const float*)d_in[1];
    float* out = (float*)d_out;
    uint4* wsb = (uint4*)d_ws;                   // 384 KiB: 3 limb B-frag arrays

    prepack_kernel<<<32, 256, 0, stream>>>(emb, wsb);

    const int n_tokens = in_sizes[0] / HDIM;     // 32768
    const int nblocks  = n_tokens / TPB;         // 1024

    router_kernel<<<nblocks, NTHREADS, 0, stream>>>(x, wsb, out);
}